// Round 15
// baseline (45.603 us; speedup 1.0000x reference)
//
#include <hip/hip_runtime.h>

typedef unsigned short u16;
typedef unsigned int u32;
typedef __attribute__((ext_vector_type(8))) short bf16x8;
typedef __attribute__((ext_vector_type(4))) short bf16x4v;
typedef __attribute__((ext_vector_type(4))) float f32x4;

#define NWAYS 10
#define NC 128
#define NHW 1024

__device__ __forceinline__ u16 f2bf(float f) {
  u32 u = __builtin_bit_cast(u32, f);
  return (u16)((u + 0x7fffu + ((u >> 16) & 1u)) >> 16);  // RNE
}
__device__ __forceinline__ float bf2f(u16 h) {
  u32 u = ((u32)h) << 16;
  return __builtin_bit_cast(float, u);
}

// ---------------- Kernel 1: fused support-Gram + weighted q-Gram, both pipelined ----------------
// [R13-verified body, unchanged]
__global__ __launch_bounds__(512) void k_phase1(const float* __restrict__ sup,
                                                const float* __restrict__ q,
                                                const float* __restrict__ cw,
                                                u16* __restrict__ Gpartb,
                                                float* __restrict__ mpart,
                                                u16* __restrict__ Wrawb,
                                                float* __restrict__ ss,
                                                float* __restrict__ out) {
  __shared__ u16 smem[NC * 256];  // 64 KiB
  __shared__ float saux[NC];
  int bid = blockIdx.x;
  int t = threadIdx.x;
  int w = t >> 6, l = t & 63, lr = l & 15, lg = l >> 4;

  if (bid < 100) {
    // ---- support Gram over one 512-n chunk: 4 pipelined chunks of 128 n ----
    int j = bid / 10, cid = bid % 10;
    int shot = cid >> 1, p0 = (cid & 1) * 512;
    const float* base = sup + ((size_t)(j * 5 + shot) * NC) * NHW + p0;
    u16* traw = smem;  // [c][128n] swizzled, 32 KiB

    float4 v[8];
    auto load_chunk = [&](int chunk) {
#pragma unroll
      for (int it = 0; it < 8; ++it) {
        int idx = it * 512 + t;
        int c = idx >> 5, pos = idx & 31;
        v[it] = *(const float4*)(base + (size_t)c * NHW + chunk * 128 + pos * 4);
      }
    };
    auto store_chunk = [&](int chunk) {
      (void)chunk;
#pragma unroll
      for (int it = 0; it < 8; ++it) {
        int idx = it * 512 + t;
        int c = idx >> 5, pos = idx & 31;
        float4 vv = v[it];
        int nl = pos * 4;
        int off = c * 128 + (((nl >> 3) ^ (c & 15)) << 3) + (nl & 7);
        bf16x4v hr;
        hr[0] = (short)f2bf(vv.x); hr[1] = (short)f2bf(vv.y);
        hr[2] = (short)f2bf(vv.z); hr[3] = (short)f2bf(vv.w);
        *(bf16x4v*)&traw[off] = hr;
        float s = vv.x + vv.y + vv.z + vv.w;
#pragma unroll
        for (int m = 1; m <= 16; m <<= 1) s += __shfl_xor(s, m, 64);
        if ((l & 31) == 0) saux[c] += s;
      }
    };

    load_chunk(0);
    if (t < NC) saux[t] = 0.f;
    __syncthreads();
    store_chunk(0);
    __syncthreads();

    f32x4 acc[8];
#pragma unroll
    for (int bt = 0; bt < 8; ++bt) acc[bt] = (f32x4){0.f, 0.f, 0.f, 0.f};
#pragma unroll 1
    for (int chunk = 0; chunk < 4; ++chunk) {
      if (chunk < 3) load_chunk(chunk + 1);
#pragma unroll
      for (int kb = 0; kb < 4; ++kb) {
        int nn = kb * 32 + lg * 8;
        int arow = w * 16 + lr;
        bf16x8 fa = *(const bf16x8*)&traw[arow * 128 + (((nn >> 3) ^ (arow & 15)) << 3)];
        bf16x8 fb[8];
#pragma unroll
        for (int bt = 0; bt < 8; ++bt) {
          int drow = bt * 16 + lr;
          fb[bt] = *(const bf16x8*)&traw[drow * 128 + (((nn >> 3) ^ (drow & 15)) << 3)];
        }
#pragma unroll
        for (int bt = 0; bt < 8; ++bt)
          acc[bt] = __builtin_amdgcn_mfma_f32_16x16x32_bf16(fa, fb[bt], acc[bt], 0, 0, 0);
      }
      __syncthreads();
      if (chunk < 3) { store_chunk(chunk + 1); __syncthreads(); }
    }

    if (t < NC) mpart[(size_t)bid * NC + t] = saux[t];
    u16* gp = Gpartb + ((size_t)bid << 14);
#pragma unroll
    for (int bt = 0; bt < 8; ++bt)
#pragma unroll
      for (int r = 0; r < 4; ++r) {
        int cr = w * 16 + lg * 4 + r;
        int d = bt * 16 + lr;
        gp[cr * NC + d] = f2bf(acc[bt][r]);
      }
  } else {
    // ---- weighted q-Gram over one 512-p half ----
    int bid2 = bid - 100;
    if (bid2 < 2) {  // zero out (640 floats) for k_wndot2's atomicAdd
      int o = bid2 * 512 + t;
      if (o < 64 * NWAYS) out[o] = 0.f;
    }
    int b = bid2 >> 1, half = bid2 & 1;
    u16* traw = smem;
    u16* twgt = smem + 16384;
    const float* base = q + (size_t)b * NC * NHW + half * 512;
    const float* cwb = cw + half * 512;

    float4 v[8];
    auto load_chunk = [&](int chunk) {
#pragma unroll
      for (int it = 0; it < 8; ++it) {
        int idx = it * 512 + t;
        int c = idx >> 5, pos = idx & 31;
        v[it] = *(const float4*)(base + (size_t)c * NHW + chunk * 128 + pos * 4);
      }
    };
    auto store_chunk = [&](int chunk) {
#pragma unroll
      for (int it = 0; it < 8; ++it) {
        int idx = it * 512 + t;
        int c = idx >> 5, pos = idx & 31;
        float4 vv = v[it];
        float4 wv = *(const float4*)(cwb + chunk * 128 + pos * 4);
        int nl = pos * 4;
        int off = c * 128 + (((nl >> 3) ^ (c & 15)) << 3) + (nl & 7);
        bf16x4v hr, hw;
        hr[0] = (short)f2bf(vv.x); hr[1] = (short)f2bf(vv.y);
        hr[2] = (short)f2bf(vv.z); hr[3] = (short)f2bf(vv.w);
        hw[0] = (short)f2bf(vv.x * wv.x); hw[1] = (short)f2bf(vv.y * wv.y);
        hw[2] = (short)f2bf(vv.z * wv.z); hw[3] = (short)f2bf(vv.w * wv.w);
        *(bf16x4v*)&traw[off] = hr;
        *(bf16x4v*)&twgt[off] = hw;
        float s = vv.x * vv.x + vv.y * vv.y + vv.z * vv.z + vv.w * vv.w;
#pragma unroll
        for (int m = 1; m <= 16; m <<= 1) s += __shfl_xor(s, m, 64);
        if ((l & 31) == 0) saux[c] += s;
      }
    };

    load_chunk(0);
    if (t < NC) saux[t] = 0.f;
    __syncthreads();
    store_chunk(0);
    __syncthreads();

    f32x4 acc[8];
#pragma unroll
    for (int bt = 0; bt < 8; ++bt) acc[bt] = (f32x4){0.f, 0.f, 0.f, 0.f};
#pragma unroll 1
    for (int chunk = 0; chunk < 4; ++chunk) {
      if (chunk < 3) load_chunk(chunk + 1);
#pragma unroll
      for (int kb = 0; kb < 4; ++kb) {
        int nn = kb * 32 + lg * 8;
        int arow = w * 16 + lr;
        bf16x8 fa = *(const bf16x8*)&twgt[arow * 128 + (((nn >> 3) ^ (arow & 15)) << 3)];
        bf16x8 fb[8];
#pragma unroll
        for (int bt = 0; bt < 8; ++bt) {
          int drow = bt * 16 + lr;
          fb[bt] = *(const bf16x8*)&traw[drow * 128 + (((nn >> 3) ^ (drow & 15)) << 3)];
        }
#pragma unroll
        for (int bt = 0; bt < 8; ++bt)
          acc[bt] = __builtin_amdgcn_mfma_f32_16x16x32_bf16(fa, fb[bt], acc[bt], 0, 0, 0);
      }
      __syncthreads();
      if (chunk < 3) { store_chunk(chunk + 1); __syncthreads(); }
    }

    if (t < NC) ss[(size_t)(half * 64 + b) * NC + t] = saux[t];
    u16* wb = Wrawb + ((size_t)(half * 64 + b) << 14);
#pragma unroll
    for (int bt = 0; bt < 8; ++bt)
#pragma unroll
      for (int r = 0; r < 4; ++r) {
        int cr = w * 16 + lg * 4 + r;
        int d = bt * 16 + lr;
        wb[cr * NC + d] = f2bf(acc[bt][r]);
      }
  }
}

// ---------------- Kernel 2: fused cov-reduce (L2-resident) + Wn dot ----------------
// grid = 64: rg = bid>>4 (32-row cov slice), bg = bid&15 (4 b's). block 512.
// LDS: cov slice bf16 for all 10 j (80 KB) + msd (5 KB) + rnl (2 KB) + red.
__global__ __launch_bounds__(512) void k_wndot2(const u16* __restrict__ Gpartb,
                                                const float* __restrict__ mpart,
                                                const u16* __restrict__ Wrawb,
                                                const float* __restrict__ ss,
                                                float* __restrict__ out) {
  __shared__ u16 covs[NWAYS * 32 * NC];  // 80 KiB: [j][r][d] bf16
  __shared__ float msd[NWAYS * NC];      // 5 KiB
  __shared__ float rnl[4 * NC];          // 2 KiB: rn for 4 b's
  __shared__ float red[8 * NWAYS];
  int bid = blockIdx.x;
  int rg = bid >> 4, bg = bid & 15;
  int t = threadIdx.x;
  int w = t >> 6, l = t & 63;

  // msd[j][c] = sum_k mpart[j*10+k][c]
  for (int idx = t; idx < NWAYS * NC; idx += 512) {
    int j = idx >> 7, c = idx & 127;
    float s = 0.f;
#pragma unroll
    for (int k = 0; k < 10; ++k) s += mpart[(size_t)(j * 10 + k) * NC + c];
    msd[idx] = s;
  }
  // rnl for 4 b's
  {
    int bb = t >> 7, c = t & 127;
    int b = bg * 4 + bb;
    rnl[t] = rsqrtf(ss[(size_t)b * NC + c] + ss[(size_t)(64 + b) * NC + c]);
  }
  __syncthreads();

  // cov slice: 10 j x 32 r x 128 d ; 20 passes of 2048 elems (bf16x4 per thread)
#pragma unroll 1
  for (int i = 0; i < 20; ++i) {
    int gpos = i * 2048 + t * 4;
    int j = gpos >> 12, r = (gpos & 4095) >> 7, d0 = gpos & 127;
    int c = rg * 32 + r;
    float g[4] = {0.f, 0.f, 0.f, 0.f};
#pragma unroll
    for (int k = 0; k < 10; ++k) {
      bf16x4v v = *(const bf16x4v*)(Gpartb + (((size_t)(j * 10 + k)) << 14) + c * NC + d0);
#pragma unroll
      for (int e = 0; e < 4; ++e) g[e] += bf2f((u16)v[e]);
    }
    float mc = msd[j * NC + c];
    bf16x4v o;
#pragma unroll
    for (int e = 0; e < 4; ++e)
      o[e] = (short)f2bf((g[e] - mc * msd[j * NC + d0 + e] * (1.0f / 5120.0f)) * (1.0f / 5119.0f));
    *(bf16x4v*)&covs[gpos] = o;
  }
  __syncthreads();

  // per-b: wn slice in registers, dot with 10 LDS covs
#pragma unroll 1
  for (int bb = 0; bb < 4; ++bb) {
    int b = bg * 4 + bb;
    int epos = t * 8;  // 4096 elems / 512 thr
    int r = epos >> 7, d0 = epos & 127;
    int c = rg * 32 + r;
    float wn[8];
    {
      bf16x8 w0 = *(const bf16x8*)(Wrawb + ((size_t)b << 14) + c * NC + d0);
      bf16x8 w1 = *(const bf16x8*)(Wrawb + ((size_t)(64 + b) << 14) + c * NC + d0);
      float rc = rnl[bb * NC + c];
#pragma unroll
      for (int e = 0; e < 8; ++e)
        wn[e] = (bf2f((u16)w0[e]) + bf2f((u16)w1[e])) * rc * rnl[bb * NC + d0 + e];
    }
    float acc[NWAYS];
#pragma unroll
    for (int j = 0; j < NWAYS; ++j) {
      bf16x8 cv = *(const bf16x8*)&covs[j * 4096 + epos];
      float s = 0.f;
#pragma unroll
      for (int e = 0; e < 8; ++e) s += wn[e] * bf2f((u16)cv[e]);
      acc[j] = s;
    }
#pragma unroll
    for (int j = 0; j < NWAYS; ++j)
#pragma unroll
      for (int m = 1; m <= 32; m <<= 1) acc[j] += __shfl_xor(acc[j], m, 64);
    if (l == 0)
#pragma unroll
      for (int j = 0; j < NWAYS; ++j) red[w * NWAYS + j] = acc[j];
    __syncthreads();
    if (t < NWAYS) {
      float s = 0.f;
#pragma unroll
      for (int wv = 0; wv < 8; ++wv) s += red[wv * NWAYS + t];
      atomicAdd(&out[b * NWAYS + t], s);
    }
    __syncthreads();
  }
}

extern "C" void kernel_launch(void* const* d_in, const int* in_sizes, int n_in,
                              void* d_out, int out_size, void* d_ws, size_t ws_size,
                              hipStream_t stream) {
  (void)in_sizes; (void)n_in; (void)out_size; (void)ws_size;
  const float* q = (const float*)d_in[0];
  const float* sup = (const float*)d_in[1];
  const float* cw = (const float*)d_in[2];
  float* out = (float*)d_out;

  char* p = (char*)d_ws;
  u16* Gpartb = (u16*)p;    p += (size_t)100 * 16384 * 2;  // 3.28 MB (L2-resident)
  float* mpart = (float*)p; p += (size_t)100 * 128 * 4;
  u16* Wrawb = (u16*)p;     p += (size_t)128 * 16384 * 2;  // 4.19 MB
  float* ssb = (float*)p;

  k_phase1<<<228, 512, 0, stream>>>(sup, q, cw, Gpartb, mpart, Wrawb, ssb, out);
  k_wndot2<<<64, 512, 0, stream>>>(Gpartb, mpart, Wrawb, ssb, out);
}

// Round 16
// 30.314 us; speedup vs baseline: 1.5044x; 1.5044x over previous
//
#include <hip/hip_runtime.h>

typedef unsigned short u16;
typedef unsigned int u32;
typedef __attribute__((ext_vector_type(8))) short bf16x8;
typedef __attribute__((ext_vector_type(4))) short bf16x4v;
typedef __attribute__((ext_vector_type(4))) float f32x4;

#define NWAYS 10
#define NC 128
#define NHW 1024

__device__ __forceinline__ u16 f2bf(float f) {
  u32 u = __builtin_bit_cast(u32, f);
  return (u16)((u + 0x7fffu + ((u >> 16) & 1u)) >> 16);  // RNE
}
__device__ __forceinline__ float bf2f(u16 h) {
  u32 u = ((u32)h) << 16;
  return __builtin_bit_cast(float, u);
}

// ---------------- Kernel 1: fused support-Gram + weighted q-Gram, both pipelined ----------------
// blocks 0..99    : Gpartb[j*10+cid] = bf16 Gram of a 512-n support chunk, 4x128-n pipelined
//                   (reg-prefetch next chunk during MFMA) ; mpart = f32 rowsums over 512 n
// blocks 100..227 : Wrawb[half*64+b] = bf16 sum_p w_p q_c q_d over 512-p half (4-chunk pipeline) ;
//                   ss[half*64+b] = sum q_c^2
// block = 512 threads (8 waves)
__global__ __launch_bounds__(512) void k_phase1(const float* __restrict__ sup,
                                                const float* __restrict__ q,
                                                const float* __restrict__ cw,
                                                u16* __restrict__ Gpartb,
                                                float* __restrict__ mpart,
                                                u16* __restrict__ Wrawb,
                                                float* __restrict__ ss,
                                                float* __restrict__ out) {
  __shared__ u16 smem[NC * 256];  // 64 KiB (q-gram uses both halves; Gram uses first 32 KiB)
  __shared__ float saux[NC];
  int bid = blockIdx.x;
  int t = threadIdx.x;
  int w = t >> 6, l = t & 63, lr = l & 15, lg = l >> 4;

  if (bid < 100) {
    // ---- support Gram over one 512-n chunk: 4 pipelined chunks of 128 n ----
    int j = bid / 10, cid = bid % 10;
    int shot = cid >> 1, p0 = (cid & 1) * 512;
    const float* base = sup + ((size_t)(j * 5 + shot) * NC) * NHW + p0;
    u16* traw = smem;  // [c][128n] swizzled, 32 KiB

    float4 v[8];
    auto load_chunk = [&](int chunk) {
#pragma unroll
      for (int it = 0; it < 8; ++it) {
        int idx = it * 512 + t;
        int c = idx >> 5, pos = idx & 31;  // 32 float4 per 128-n row
        v[it] = *(const float4*)(base + (size_t)c * NHW + chunk * 128 + pos * 4);
      }
    };
    auto store_chunk = [&](int chunk) {
      (void)chunk;
#pragma unroll
      for (int it = 0; it < 8; ++it) {
        int idx = it * 512 + t;
        int c = idx >> 5, pos = idx & 31;
        float4 vv = v[it];
        int nl = pos * 4;
        int off = c * 128 + (((nl >> 3) ^ (c & 15)) << 3) + (nl & 7);
        bf16x4v hr;
        hr[0] = (short)f2bf(vv.x); hr[1] = (short)f2bf(vv.y);
        hr[2] = (short)f2bf(vv.z); hr[3] = (short)f2bf(vv.w);
        *(bf16x4v*)&traw[off] = hr;
        float s = vv.x + vv.y + vv.z + vv.w;
#pragma unroll
        for (int m = 1; m <= 16; m <<= 1) s += __shfl_xor(s, m, 64);
        if ((l & 31) == 0) saux[c] += s;  // unique writer per (chunk,c)
      }
    };

    load_chunk(0);
    if (t < NC) saux[t] = 0.f;
    __syncthreads();  // init visible before any +=
    store_chunk(0);
    __syncthreads();

    f32x4 acc[8];
#pragma unroll
    for (int bt = 0; bt < 8; ++bt) acc[bt] = (f32x4){0.f, 0.f, 0.f, 0.f};
#pragma unroll 1
    for (int chunk = 0; chunk < 4; ++chunk) {
      if (chunk < 3) load_chunk(chunk + 1);  // issue-early: HBM hides under MFMA
#pragma unroll
      for (int kb = 0; kb < 4; ++kb) {
        int nn = kb * 32 + lg * 8;
        int arow = w * 16 + lr;  // 8 waves x 16 rows = 128
        bf16x8 fa = *(const bf16x8*)&traw[arow * 128 + (((nn >> 3) ^ (arow & 15)) << 3)];
        bf16x8 fb[8];
#pragma unroll
        for (int bt = 0; bt < 8; ++bt) {
          int drow = bt * 16 + lr;
          fb[bt] = *(const bf16x8*)&traw[drow * 128 + (((nn >> 3) ^ (drow & 15)) << 3)];
        }
#pragma unroll
        for (int bt = 0; bt < 8; ++bt)
          acc[bt] = __builtin_amdgcn_mfma_f32_16x16x32_bf16(fa, fb[bt], acc[bt], 0, 0, 0);
      }
      __syncthreads();
      if (chunk < 3) { store_chunk(chunk + 1); __syncthreads(); }
    }

    if (t < NC) mpart[(size_t)bid * NC + t] = saux[t];
    u16* gp = Gpartb + ((size_t)bid << 14);
#pragma unroll
    for (int bt = 0; bt < 8; ++bt)
#pragma unroll
      for (int r = 0; r < 4; ++r) {
        int cr = w * 16 + lg * 4 + r;  // C/D: row=(lane>>4)*4+reg
        int d = bt * 16 + lr;          //      col=lane&15
        gp[cr * NC + d] = f2bf(acc[bt][r]);
      }
  } else {
    // ---- weighted q-Gram over one 512-p half (4 chunks of 128 p, pipelined) ----
    int bid2 = bid - 100;
    if (bid2 < 2) {  // zero out (640 floats) for k_wndot's atomicAdd
      int o = bid2 * 512 + t;
      if (o < 64 * NWAYS) out[o] = 0.f;
    }
    int b = bid2 >> 1, half = bid2 & 1;
    u16* traw = smem;          // [c][128p] swizzled
    u16* twgt = smem + 16384;  // w_p-scaled
    const float* base = q + (size_t)b * NC * NHW + half * 512;
    const float* cwb = cw + half * 512;

    float4 v[8];
    auto load_chunk = [&](int chunk) {
#pragma unroll
      for (int it = 0; it < 8; ++it) {
        int idx = it * 512 + t;
        int c = idx >> 5, pos = idx & 31;  // 32 float4 per 128-p row
        v[it] = *(const float4*)(base + (size_t)c * NHW + chunk * 128 + pos * 4);
      }
    };
    auto store_chunk = [&](int chunk) {
#pragma unroll
      for (int it = 0; it < 8; ++it) {
        int idx = it * 512 + t;
        int c = idx >> 5, pos = idx & 31;
        float4 vv = v[it];
        float4 wv = *(const float4*)(cwb + chunk * 128 + pos * 4);
        int nl = pos * 4;
        int off = c * 128 + (((nl >> 3) ^ (c & 15)) << 3) + (nl & 7);
        bf16x4v hr, hw;
        hr[0] = (short)f2bf(vv.x); hr[1] = (short)f2bf(vv.y);
        hr[2] = (short)f2bf(vv.z); hr[3] = (short)f2bf(vv.w);
        hw[0] = (short)f2bf(vv.x * wv.x); hw[1] = (short)f2bf(vv.y * wv.y);
        hw[2] = (short)f2bf(vv.z * wv.z); hw[3] = (short)f2bf(vv.w * wv.w);
        *(bf16x4v*)&traw[off] = hr;
        *(bf16x4v*)&twgt[off] = hw;
        float s = vv.x * vv.x + vv.y * vv.y + vv.z * vv.z + vv.w * vv.w;
#pragma unroll
        for (int m = 1; m <= 16; m <<= 1) s += __shfl_xor(s, m, 64);
        if ((l & 31) == 0) saux[c] += s;  // unique writer per (chunk,c)
      }
    };

    load_chunk(0);
    if (t < NC) saux[t] = 0.f;
    __syncthreads();  // init visible before any +=
    store_chunk(0);
    __syncthreads();

    f32x4 acc[8];
#pragma unroll
    for (int bt = 0; bt < 8; ++bt) acc[bt] = (f32x4){0.f, 0.f, 0.f, 0.f};
#pragma unroll 1
    for (int chunk = 0; chunk < 4; ++chunk) {
      if (chunk < 3) load_chunk(chunk + 1);  // issue-early: HBM hides under MFMA
#pragma unroll
      for (int kb = 0; kb < 4; ++kb) {
        int nn = kb * 32 + lg * 8;
        int arow = w * 16 + lr;
        bf16x8 fa = *(const bf16x8*)&twgt[arow * 128 + (((nn >> 3) ^ (arow & 15)) << 3)];
        bf16x8 fb[8];
#pragma unroll
        for (int bt = 0; bt < 8; ++bt) {
          int drow = bt * 16 + lr;
          fb[bt] = *(const bf16x8*)&traw[drow * 128 + (((nn >> 3) ^ (drow & 15)) << 3)];
        }
#pragma unroll
        for (int bt = 0; bt < 8; ++bt)
          acc[bt] = __builtin_amdgcn_mfma_f32_16x16x32_bf16(fa, fb[bt], acc[bt], 0, 0, 0);
      }
      __syncthreads();
      if (chunk < 3) { store_chunk(chunk + 1); __syncthreads(); }
    }

    if (t < NC) ss[(size_t)(half * 64 + b) * NC + t] = saux[t];
    u16* wb = Wrawb + ((size_t)(half * 64 + b) << 14);
#pragma unroll
    for (int bt = 0; bt < 8; ++bt)
#pragma unroll
      for (int r = 0; r < 4; ++r) {
        int cr = w * 16 + lg * 4 + r;
        int d = bt * 16 + lr;
        wb[cr * NC + d] = f2bf(acc[bt][r]);
      }
  }
}

// ---------------- Kernel 2: reduce 10 Gram partials -> bf16 cov ----------------
// grid = 10 j * 16 rowgroups of 8 rows ; block 256 (each thread: 4 consecutive d)
__global__ __launch_bounds__(256) void k_fin(const u16* __restrict__ Gpartb,
                                             const float* __restrict__ mpart,
                                             u16* __restrict__ covb) {
  __shared__ float msd[NC];
  int j = blockIdx.x >> 4, rg = blockIdx.x & 15;
  int t = threadIdx.x;
  if (t < NC) {
    float s = 0.f;
#pragma unroll
    for (int k = 0; k < 10; ++k) s += mpart[(size_t)(j * 10 + k) * NC + t];
    msd[t] = s;
  }
  __syncthreads();
  int e = rg * 1024 + t * 4;  // 8 rows x 128 cols per block
  int c = e >> 7, d0 = e & 127;
  float g[4] = {0.f, 0.f, 0.f, 0.f};
#pragma unroll
  for (int k = 0; k < 10; ++k) {
    bf16x4v v = *(const bf16x4v*)(Gpartb + (((size_t)(j * 10 + k)) << 14) + e);
#pragma unroll
    for (int r = 0; r < 4; ++r) g[r] += bf2f((u16)v[r]);
  }
  bf16x4v o;
#pragma unroll
  for (int r = 0; r < 4; ++r)
    o[r] = (short)f2bf((g[r] - msd[c] * msd[d0 + r] * (1.0f / 5120.0f)) * (1.0f / 5119.0f));
  *(bf16x4v*)(covb + (((size_t)j) << 14) + e) = o;
}

// ---------------- Kernel 3: Wn chunk in registers, dot with all 10 covs ----------------
// grid = 64 b * 4 rowgroups of 32 rows ; block 256 (16 consecutive elems/thread)
__global__ __launch_bounds__(256) void k_wndot(const u16* __restrict__ Wrawb,
                                               const float* __restrict__ ss,
                                               const u16* __restrict__ covb,
                                               float* __restrict__ out) {
  __shared__ float rnl[NC];
  __shared__ float red[4 * NWAYS];
  int b = blockIdx.x >> 2, rg = blockIdx.x & 3;
  int t = threadIdx.x;
  int w = t >> 6, l = t & 63;
  if (t < NC) {
    float s = ss[(size_t)b * NC + t] + ss[(size_t)(64 + b) * NC + t];
    rnl[t] = rsqrtf(s);
  }
  __syncthreads();
  int e = rg * 4096 + t * 16;  // 32 rows x 128 cols per block
  int c = e >> 7, d0 = e & 127;
  float wn[16];
#pragma unroll
  for (int k = 0; k < 16; ++k) wn[k] = 0.f;
#pragma unroll
  for (int qr = 0; qr < 2; ++qr) {
    const u16* src = Wrawb + (((size_t)(qr * 64 + b)) << 14) + e;
    bf16x8 v0 = *(const bf16x8*)src;
    bf16x8 v1 = *(const bf16x8*)(src + 8);
#pragma unroll
    for (int k = 0; k < 8; ++k) { wn[k] += bf2f((u16)v0[k]); wn[8 + k] += bf2f((u16)v1[k]); }
  }
  float rc = rnl[c];
#pragma unroll
  for (int k = 0; k < 16; ++k) wn[k] *= rc * rnl[d0 + k];

  float acc[NWAYS];
#pragma unroll
  for (int j = 0; j < NWAYS; ++j) {
    const u16* cj = covb + ((size_t)j << 14) + e;
    bf16x8 c0 = *(const bf16x8*)cj;
    bf16x8 c1 = *(const bf16x8*)(cj + 8);
    float s = 0.f;
#pragma unroll
    for (int k = 0; k < 8; ++k) s += wn[k] * bf2f((u16)c0[k]) + wn[8 + k] * bf2f((u16)c1[k]);
    acc[j] = s;
  }
#pragma unroll
  for (int j = 0; j < NWAYS; ++j)
#pragma unroll
    for (int m = 1; m <= 32; m <<= 1) acc[j] += __shfl_xor(acc[j], m, 64);
  if (l == 0)
#pragma unroll
    for (int j = 0; j < NWAYS; ++j) red[w * NWAYS + j] = acc[j];
  __syncthreads();
  if (t < NWAYS)
    atomicAdd(&out[b * NWAYS + t],
              red[t] + red[NWAYS + t] + red[2 * NWAYS + t] + red[3 * NWAYS + t]);
}

extern "C" void kernel_launch(void* const* d_in, const int* in_sizes, int n_in,
                              void* d_out, int out_size, void* d_ws, size_t ws_size,
                              hipStream_t stream) {
  (void)in_sizes; (void)n_in; (void)out_size; (void)ws_size;
  const float* q = (const float*)d_in[0];
  const float* sup = (const float*)d_in[1];
  const float* cw = (const float*)d_in[2];
  float* out = (float*)d_out;

  char* p = (char*)d_ws;
  u16* Gpartb = (u16*)p;    p += (size_t)100 * 16384 * 2;  // 3.28 MB
  float* mpart = (float*)p; p += (size_t)100 * 128 * 4;
  u16* covb = (u16*)p;      p += (size_t)10 * 16384 * 2;
  u16* Wrawb = (u16*)p;     p += (size_t)128 * 16384 * 2;  // 4.19 MB
  float* ssb = (float*)p;

  k_phase1<<<228, 512, 0, stream>>>(sup, q, cw, Gpartb, mpart, Wrawb, ssb, out);
  k_fin<<<160, 256, 0, stream>>>(Gpartb, mpart, covb);
  k_wndot<<<256, 256, 0, stream>>>(Wrawb, ssb, covb, out);
}